// Round 8
// baseline (860.330 us; speedup 1.0000x reference)
//
#include <hip/hip_runtime.h>
#include <hip/hip_bf16.h>
#include <stdint.h>

#define HID 512
#define NACT 64
#define NAG 8
#define NR 16384            // 2048 * 8 rows
#define MAXT128 136         // 128-row tiles (fc1-3)
#define MAXT64  264         // 64-row tiles (fc4)

typedef __bf16 bf16_t;
typedef __bf16 bf16x4 __attribute__((ext_vector_type(4)));
typedef __bf16 bf16x8 __attribute__((ext_vector_type(8)));
typedef float  f32x16 __attribute__((ext_vector_type(16)));

#define MFMA32(a,b,c) __builtin_amdgcn_mfma_f32_32x32x16_bf16((a),(b),(c),0,0,0)

// ---------------- workspace layout (bytes) ----------------
// meta ints: [0:8) counts, [8:16) cursors, 16 nt128, 17 nt64,
//   128-tiles: start 32..191, rows 192..351, agent 352..511
//   64-tiles:  start 512..799, rows 800..1087, agent 1088..1375
#define OFF_META 0
#define OFF_PERM 8192
#define OFF_WM1  (128*1024)
#define OFF_WM2  (OFF_WM1 + NAG*HID*HID*2)
#define OFF_WM3  (OFF_WM2 + NAG*HID*HID*2)
#define OFF_WM4  (OFF_WM3 + NAG*HID*HID*2)
#define OFF_WIH  (OFF_WM4 + NAG*NACT*HID*2)
#define OFF_WHH  (OFF_WIH + 3*HID*HID*2)
#define OFF_XS   (OFF_WHH + 3*HID*HID*2)        // h (gru out, sorted bf16); then q3
#define OFF_B1   (OFF_XS + (size_t)NR*HID*2)    // x1 (fc1 out); then q2

// ---------------- helpers ----------------
__device__ inline void load_lds16(const void* g, void* l) {
  __builtin_amdgcn_global_load_lds((__attribute__((address_space(1))) void*)g,
                                   (__attribute__((address_space(3))) void*)l,
                                   16, 0, 0);
}

// LDS tile: [R rows][64 bf16], 128B/row; 16B slot s of row r holds col-block (s ^ (r&7))
__device__ inline bf16x8 lds_frag(const bf16_t* base, int r, int cb) {
  return *(const bf16x8*)((const char*)base + r*128 + ((cb*16) ^ ((r&7)<<4)));
}
__device__ inline void store8bf(void* dst, float4 a, float4 b) {
  union { bf16_t h[8]; uint4 u; } p;
  p.h[0]=(bf16_t)a.x; p.h[1]=(bf16_t)a.y; p.h[2]=(bf16_t)a.z; p.h[3]=(bf16_t)a.w;
  p.h[4]=(bf16_t)b.x; p.h[5]=(bf16_t)b.y; p.h[6]=(bf16_t)b.z; p.h[7]=(bf16_t)b.w;
  *(uint4*)dst = p.u;
}
__device__ inline float kmask(float w, float t) {
  // t <= -3 always: sigmoid(t) = x/(1+x), x=e^t<=0.05 -> x - x^2 + x^3 (err <= 6e-6)
  float x = __expf(t);
  float x2 = x*x;
  float s = x - x2 + x2*x;
  float m = fabsf(w) - s;
  return m > 0.f ? copysignf(m, w) : 0.f;
}
__device__ inline float sigm(float x) { return 1.f / (1.f + __expf(-x)); }
__device__ inline float tanh_f(float x) {
  float e = __expf(2.f * fabsf(x));
  return copysignf(1.f - 2.f/(e + 1.f), x);
}

// ---------------- weight prep ----------------
__global__ void k_prep(const float* __restrict__ f1w, const float* __restrict__ f1t,
                       const float* __restrict__ f2w, const float* __restrict__ f2t,
                       const float* __restrict__ f3w, const float* __restrict__ f3t,
                       const float* __restrict__ f4w, const float* __restrict__ f4t,
                       const float* __restrict__ gih, const float* __restrict__ ghh,
                       bf16_t* __restrict__ wm1, bf16_t* __restrict__ wm2,
                       bf16_t* __restrict__ wm3, bf16_t* __restrict__ wm4,
                       bf16_t* __restrict__ wihb, bf16_t* __restrict__ whhb,
                       int* __restrict__ meta)
{
  const int tid = threadIdx.x;
  if (blockIdx.x == 0 && tid < 32) meta[tid] = 0;
  long v = (long)blockIdx.x * 256 + tid;
  const long VR1 = 524288;
  if (v < 3*VR1) {
    int which = (int)(v / VR1);
    long e = (v - (long)which*VR1) * 4;
    const float* W = which==0 ? f1w : (which==1 ? f2w : f3w);
    const float* T = which==0 ? f1t : (which==1 ? f2t : f3t);
    bf16_t* O = which==0 ? wm1 : (which==1 ? wm2 : wm3);
    long oi = e & (long)(HID*HID - 1);
    float4 w = *(const float4*)(W + oi);
    float4 t = *(const float4*)(T + e);
    bf16x4 o;
    o[0]=(bf16_t)kmask(w.x,t.x); o[1]=(bf16_t)kmask(w.y,t.y);
    o[2]=(bf16_t)kmask(w.z,t.z); o[3]=(bf16_t)kmask(w.w,t.w);
    *(bf16x4*)(O + e) = o;
  } else if (v < 3*VR1 + 65536) {
    long e = (v - 3*VR1) * 4;
    long oi = e & (long)(NACT*HID - 1);
    float4 w = *(const float4*)(f4w + oi);
    float4 t = *(const float4*)(f4t + e);
    bf16x4 o;
    o[0]=(bf16_t)kmask(w.x,t.x); o[1]=(bf16_t)kmask(w.y,t.y);
    o[2]=(bf16_t)kmask(w.z,t.z); o[3]=(bf16_t)kmask(w.w,t.w);
    *(bf16x4*)(wm4 + e) = o;
  } else if (v < 3*VR1 + 65536 + 196608) {
    long e = (v - (3*VR1 + 65536)) * 4;
    float4 x = *(const float4*)(gih + e);
    bf16x4 o; o[0]=(bf16_t)x.x; o[1]=(bf16_t)x.y; o[2]=(bf16_t)x.z; o[3]=(bf16_t)x.w;
    *(bf16x4*)(wihb + e) = o;
  } else if (v < 3*VR1 + 65536 + 2*196608) {
    long e = (v - (3*VR1 + 65536 + 196608)) * 4;
    float4 x = *(const float4*)(ghh + e);
    bf16x4 o; o[0]=(bf16_t)x.x; o[1]=(bf16_t)x.y; o[2]=(bf16_t)x.z; o[3]=(bf16_t)x.w;
    *(bf16x4*)(whhb + e) = o;
  }
}

// ---------------- bucket rows by agent ----------------
__global__ void k_count(const int* __restrict__ ids, int* __restrict__ meta) {
  int n = blockIdx.x*256 + threadIdx.x;
  atomicAdd(&meta[ids[n]], 1);
}

__global__ void k_td(int* __restrict__ meta) {
  int off = 0, nt = 0, nt64 = 0;
  for (int a = 0; a < NAG; ++a) {
    int c = meta[a];
    meta[8+a] = off;
    for (int t = 0; t*128 < c; ++t) {
      meta[32  + nt] = off + t*128;
      meta[192 + nt] = (c - t*128 < 128) ? (c - t*128) : 128;
      meta[352 + nt] = a;
      ++nt;
    }
    for (int t = 0; t*64 < c; ++t) {
      meta[512  + nt64] = off + t*64;
      meta[800  + nt64] = (c - t*64 < 64) ? (c - t*64) : 64;
      meta[1088 + nt64] = a;
      ++nt64;
    }
    off += c;
  }
  meta[16] = nt;
  meta[17] = nt64;
}

__global__ void k_scatter(const int* __restrict__ ids, int* __restrict__ meta,
                          int* __restrict__ perm) {
  int n = blockIdx.x*256 + threadIdx.x;
  int a = ids[n];
  int pos = atomicAdd(&meta[8+a], 1);
  perm[pos] = n;
}

// ---------------- grouped kalei GEMM: BM=128, BN=128, 4 waves, single-buffer ----------------
// Simple 2-sync full-drain loop (R1 regime): 32KB LDS -> 4 blocks/CU; implicit
// inter-block overlap hides the drains (m114). GATHER: A = fp32 rows via perm.
template<bool GATHER>
__global__ __launch_bounds__(256, 4)
void k_fc(const float* __restrict__ a_f32, const bf16_t* __restrict__ a_bf,
          const bf16_t* __restrict__ wbase, const float* __restrict__ bias,
          bf16_t* __restrict__ out_bf,
          const int* __restrict__ meta, const int* __restrict__ perm)
{
  const int bx = blockIdx.x;
  if (bx >= meta[16]) return;
  const int m0 = meta[32+bx], rows = meta[192+bx], agent = meta[352+bx];
  const int o0 = blockIdx.y * 128;
  const bf16_t* W = wbase + (size_t)agent * HID * HID;

  __shared__ bf16_t lA[128*64];
  __shared__ bf16_t lB[128*64];

  const int tid = threadIdx.x, lane = tid & 63, wid = tid >> 6;
  const int wrow = wid & 1, wcol = wid >> 1;
  const int gsw = (lane&7) ^ ((lane>>3)&7);
  const int lr8 = lane >> 3;

  f32x16 zero;
  #pragma unroll
  for (int i = 0; i < 16; ++i) zero[i] = 0.f;
  f32x16 acc[2][2];
  acc[0][0]=acc[0][1]=acc[1][0]=acc[1][1]=zero;

  for (int kp = 0; kp < 8; ++kp) {
    const int k0 = kp * 64;
    __syncthreads();
    if constexpr (GATHER) {
      #pragma unroll
      for (int it = 0; it < 4; ++it) {
        int t = it*256 + tid;
        int r = t >> 3, cb = t & 7;
        int rl = r < rows ? r : rows-1;
        const float* sp = a_f32 + (size_t)perm[m0+rl]*HID + k0 + cb*8;
        float4 v0 = ((const float4*)sp)[0];
        float4 v1 = ((const float4*)sp)[1];
        store8bf((char*)lA + r*128 + ((cb*16) ^ ((r&7)<<4)), v0, v1);
      }
    } else {
      #pragma unroll
      for (int i = 0; i < 4; ++i) {
        int c = wid*4 + i;
        int r = c*8 + lr8;
        int rl = r < rows ? r : rows-1;
        load_lds16(a_bf + (size_t)(m0+rl)*HID + k0 + gsw*8, (char*)lA + c*1024);
      }
    }
    #pragma unroll
    for (int i = 0; i < 4; ++i) {
      int c = wid*4 + i;
      int r = c*8 + lr8;
      load_lds16(W + (size_t)(o0+r)*HID + k0 + gsw*8, (char*)lB + c*1024);
    }
    __syncthreads();
    #pragma unroll
    for (int kk = 0; kk < 4; ++kk) {
      const int cbb = kk*2 + (lane>>5);
      bf16x8 af0 = lds_frag(lA, wrow*64 +      (lane&31), cbb);
      bf16x8 af1 = lds_frag(lA, wrow*64 + 32 + (lane&31), cbb);
      bf16x8 bv0 = lds_frag(lB, wcol*64 +      (lane&31), cbb);
      bf16x8 bv1 = lds_frag(lB, wcol*64 + 32 + (lane&31), cbb);
      __builtin_amdgcn_s_setprio(1);
      acc[0][0] = MFMA32(af0, bv0, acc[0][0]);
      acc[1][0] = MFMA32(af1, bv0, acc[1][0]);
      acc[0][1] = MFMA32(af0, bv1, acc[0][1]);
      acc[1][1] = MFMA32(af1, bv1, acc[1][1]);
      __builtin_amdgcn_s_setprio(0);
    }
  }

  // epilogue: relu(acc+b); C layout (32x32): col=lane&31, row=4*(lane>>5)+(g&3)+8*(g>>2)
  #pragma unroll
  for (int fn = 0; fn < 2; ++fn) {
    int col = o0 + wcol*64 + fn*32 + (lane&31);
    float bv = bias[col];
    #pragma unroll
    for (int fm = 0; fm < 2; ++fm) {
      #pragma unroll
      for (int g = 0; g < 16; ++g) {
        int rl = wrow*64 + fm*32 + 4*(lane>>5) + (g&3) + 8*(g>>2);
        if (rl < rows) {
          float y = fmaxf(acc[fm][fn][g] + bv, 0.f);
          out_bf[(size_t)(m0+rl)*HID + col] = (bf16_t)y;
        }
      }
    }
  }
}

// ---------------- fused GRU: BM=128, BN=64, 4 waves, single-buffer ----------------
// grid (128, 8); 40KB LDS -> 4 blocks/CU. H-phase A gathered fp32->bf16 via perm.
__global__ __launch_bounds__(256, 4)
void k_gru(const bf16_t* __restrict__ x1, const float* __restrict__ hidden,
           const bf16_t* __restrict__ wih, const bf16_t* __restrict__ whh,
           const float* __restrict__ bih, const float* __restrict__ bhh,
           bf16_t* __restrict__ hbuf, float* __restrict__ hout,
           const int* __restrict__ perm)
{
  const int m0 = blockIdx.x * 128;
  const int j0 = blockIdx.y * 64;
  const int tid = threadIdx.x, lane = tid & 63, wid = tid >> 6;
  const int wrow = wid & 1, wcol = wid >> 1;
  const int gsw = (lane&7) ^ ((lane>>3)&7);
  const int lr8 = lane >> 3;

  __shared__ bf16_t lA[128*64];
  __shared__ bf16_t lB[192*64];

  f32x16 zero;
  #pragma unroll
  for (int i = 0; i < 16; ++i) zero[i] = 0.f;
  f32x16 ar[2], az[2], an[2], ah[2];
  ar[0]=ar[1]=az[0]=az[1]=an[0]=an[1]=ah[0]=ah[1]=zero;

  for (int kp = 0; kp < 16; ++kp) {
    const bf16_t* Wg = (kp < 8) ? wih : whh;
    const int k0 = (kp & 7) * 64;
    __syncthreads();
    if (kp < 8) {            // X phase: A = x1 (sorted bf16) via glds
      #pragma unroll
      for (int i = 0; i < 4; ++i) {
        int c = wid*4 + i;
        int r = c*8 + lr8;
        load_lds16(x1 + (size_t)(m0+r)*HID + k0 + gsw*8, (char*)lA + c*1024);
      }
    } else {                 // H phase: A = hidden fp32 gathered via perm
      #pragma unroll
      for (int it = 0; it < 4; ++it) {
        int t = it*256 + tid;
        int r = t >> 3, cb = t & 7;
        const float* sp = hidden + (size_t)perm[m0+r]*HID + k0 + cb*8;
        float4 v0 = ((const float4*)sp)[0];
        float4 v1 = ((const float4*)sp)[1];
        store8bf((char*)lA + r*128 + ((cb*16) ^ ((r&7)<<4)), v0, v1);
      }
    }
    #pragma unroll
    for (int i = 0; i < 6; ++i) {
      int c = wid*6 + i;                // 24 chunks: rows 0..191 = gate*64 + within
      int r = c*8 + lr8;
      int wr = (r>>6)*HID + j0 + (r&63);
      load_lds16(Wg + (size_t)wr*HID + k0 + gsw*8, (char*)lB + c*1024);
    }
    __syncthreads();
    f32x16* a3 = (kp < 8) ? an : ah;
    #pragma unroll
    for (int kk = 0; kk < 4; ++kk) {
      const int cbb = kk*2 + (lane>>5);
      bf16x8 af0 = lds_frag(lA, wrow*64 +      (lane&31), cbb);
      bf16x8 af1 = lds_frag(lA, wrow*64 + 32 + (lane&31), cbb);
      const int rb = wcol*32 + (lane&31);
      bf16x8 b0 = lds_frag(lB,        rb, cbb);
      bf16x8 b1 = lds_frag(lB + 4096, rb, cbb);
      bf16x8 b2 = lds_frag(lB + 8192, rb, cbb);
      __builtin_amdgcn_s_setprio(1);
      ar[0] = MFMA32(af0, b0, ar[0]); ar[1] = MFMA32(af1, b0, ar[1]);
      az[0] = MFMA32(af0, b1, az[0]); az[1] = MFMA32(af1, b1, az[1]);
      a3[0] = MFMA32(af0, b2, a3[0]); a3[1] = MFMA32(af1, b2, a3[1]);
      __builtin_amdgcn_s_setprio(0);
    }
  }

  // ---- epilogue: gates + blend (h_prev exact fp32) ----
  const int col = j0 + wcol*32 + (lane&31);
  const float b_r  = bih[col]        + bhh[col];
  const float b_z  = bih[512 + col]  + bhh[512 + col];
  const float b_in = bih[1024 + col];
  const float b_hn = bhh[1024 + col];
  #pragma unroll
  for (int fm = 0; fm < 2; ++fm) {
    #pragma unroll
    for (int g = 0; g < 16; ++g) {
      int rl = wrow*64 + fm*32 + 4*(lane>>5) + (g&3) + 8*(g>>2);
      int m = m0 + rl;
      int src = perm[m];
      float hp = hidden[(size_t)src*HID + col];
      float rg = sigm(ar[fm][g] + b_r);
      float zg = sigm(az[fm][g] + b_z);
      float ng = tanh_f(an[fm][g] + b_in + rg*(ah[fm][g] + b_hn));
      float h  = (1.f - zg)*ng + zg*hp;
      hbuf[(size_t)m*HID + col] = (bf16_t)h;
      hout[(size_t)src*HID + col] = h;
    }
  }
}

// ---------------- fc4: BM=64, BN=64, 4 waves (2x2, tile 32x32), single-buffer ----------------
__global__ __launch_bounds__(256, 4)
void k_fc4(const bf16_t* __restrict__ a_bf, const bf16_t* __restrict__ wbase,
           const float* __restrict__ bias, float* __restrict__ out_f32,
           const int* __restrict__ meta, const int* __restrict__ perm)
{
  const int bx = blockIdx.x;
  if (bx >= meta[17]) return;
  const int m0 = meta[512+bx], rows = meta[800+bx], agent = meta[1088+bx];
  const bf16_t* W = wbase + (size_t)agent * NACT * HID;

  __shared__ bf16_t lA[64*64];
  __shared__ bf16_t lB[64*64];

  const int tid = threadIdx.x, lane = tid & 63, wid = tid >> 6;
  const int wrow = wid & 1, wcol = wid >> 1;
  const int gsw = (lane&7) ^ ((lane>>3)&7);
  const int lr8 = lane >> 3;

  f32x16 acc;
  #pragma unroll
  for (int i = 0; i < 16; ++i) acc[i] = 0.f;

  for (int kp = 0; kp < 8; ++kp) {
    const int k0 = kp * 64;
    __syncthreads();
    #pragma unroll
    for (int i = 0; i < 2; ++i) {
      int c = wid*2 + i;
      int r = c*8 + lr8;
      int rl = r < rows ? r : rows-1;
      load_lds16(a_bf + (size_t)(m0+rl)*HID + k0 + gsw*8, (char*)lA + c*1024);
    }
    #pragma unroll
    for (int i = 0; i < 2; ++i) {
      int c = wid*2 + i;
      int r = c*8 + lr8;
      load_lds16(W + (size_t)r*HID + k0 + gsw*8, (char*)lB + c*1024);
    }
    __syncthreads();
    #pragma unroll
    for (int kk = 0; kk < 4; ++kk) {
      const int cbb = kk*2 + (lane>>5);
      bf16x8 af = lds_frag(lA, wrow*32 + (lane&31), cbb);
      bf16x8 bv = lds_frag(lB, wcol*32 + (lane&31), cbb);
      __builtin_amdgcn_s_setprio(1);
      acc = MFMA32(af, bv, acc);
      __builtin_amdgcn_s_setprio(0);
    }
  }

  int col = wcol*32 + (lane&31);
  float bv = bias[col];
  #pragma unroll
  for (int g = 0; g < 16; ++g) {
    int rl = wrow*32 + 4*(lane>>5) + (g&3) + 8*(g>>2);
    if (rl < rows)
      out_f32[(size_t)perm[m0+rl]*NACT + col] = acc[g] + bv;
  }
}

// ---------------- launch ----------------
extern "C" void kernel_launch(void* const* d_in, const int* in_sizes, int n_in,
                              void* d_out, int out_size, void* d_ws, size_t ws_size,
                              hipStream_t stream) {
  const float* inputs  = (const float*)d_in[0];
  const float* hidden  = (const float*)d_in[1];
  const int*   ids     = (const int*)  d_in[2];
  const float* fc1_w   = (const float*)d_in[3];
  const float* fc1_b   = (const float*)d_in[4];
  const float* fc1_t   = (const float*)d_in[5];
  const float* gru_wih = (const float*)d_in[6];
  const float* gru_whh = (const float*)d_in[7];
  const float* gru_bih = (const float*)d_in[8];
  const float* gru_bhh = (const float*)d_in[9];
  const float* fc2_w   = (const float*)d_in[10];
  const float* fc2_b   = (const float*)d_in[11];
  const float* fc2_t   = (const float*)d_in[12];
  const float* fc3_w   = (const float*)d_in[13];
  const float* fc3_b   = (const float*)d_in[14];
  const float* fc3_t   = (const float*)d_in[15];
  const float* fc4_w   = (const float*)d_in[16];
  const float* fc4_b   = (const float*)d_in[17];
  const float* fc4_t   = (const float*)d_in[18];

  char* ws = (char*)d_ws;
  int*    meta = (int*)   (ws + OFF_META);
  int*    perm = (int*)   (ws + OFF_PERM);
  bf16_t* wm1  = (bf16_t*)(ws + OFF_WM1);
  bf16_t* wm2  = (bf16_t*)(ws + OFF_WM2);
  bf16_t* wm3  = (bf16_t*)(ws + OFF_WM3);
  bf16_t* wm4  = (bf16_t*)(ws + OFF_WM4);
  bf16_t* wihb = (bf16_t*)(ws + OFF_WIH);
  bf16_t* whhb = (bf16_t*)(ws + OFF_WHH);
  bf16_t* xs   = (bf16_t*)(ws + OFF_XS);   // h, then q3
  bf16_t* b1   = (bf16_t*)(ws + OFF_B1);   // x1, then q2

  float* q_out = (float*)d_out;                 // [NR][64]
  float* h_out = q_out + (size_t)NR * NACT;     // [NR][512]

  k_prep<<<7936, 256, 0, stream>>>(fc1_w, fc1_t, fc2_w, fc2_t, fc3_w, fc3_t,
                                   fc4_w, fc4_t, gru_wih, gru_whh,
                                   wm1, wm2, wm3, wm4, wihb, whhb, meta);
  k_count<<<64, 256, 0, stream>>>(ids, meta);
  k_td<<<1, 1, 0, stream>>>(meta);
  k_scatter<<<64, 256, 0, stream>>>(ids, meta, perm);

  // fc1: gather fp32 inputs -> b1 (x1 sorted bf16)
  k_fc<true><<<dim3(MAXT128, 4), 256, 0, stream>>>(
      inputs, nullptr, wm1, fc1_b, b1, meta, perm);
  // GRU: b1 + gathered hidden -> xs (h sorted bf16) + h_out (fp32 scattered)
  k_gru<<<dim3(NR/128, 8), 256, 0, stream>>>(b1, hidden, wihb, whhb,
                                             gru_bih, gru_bhh, xs, h_out, perm);
  // fc2: xs -> b1 (q2)
  k_fc<false><<<dim3(MAXT128, 4), 256, 0, stream>>>(
      nullptr, xs, wm2, fc2_b, b1, meta, perm);
  // fc3: b1 -> xs (q3)
  k_fc<false><<<dim3(MAXT128, 4), 256, 0, stream>>>(
      nullptr, b1, wm3, fc3_b, xs, meta, perm);
  // fc4: xs -> q_out (fp32 scattered, no relu)
  k_fc4<<<dim3(MAXT64, 1), 256, 0, stream>>>(xs, wm4, fc4_b, q_out, meta, perm);
}

// Round 9
// 554.165 us; speedup vs baseline: 1.5525x; 1.5525x over previous
//
#include <hip/hip_runtime.h>
#include <hip/hip_bf16.h>
#include <stdint.h>

#define HID 512
#define NACT 64
#define NAG 8
#define NR 16384            // 2048 * 8 rows
#define MAXT128 136         // 128-row tiles (fc1-3)
#define MAXT64  264         // 64-row tiles (fc4)

typedef __bf16 bf16_t;
typedef __bf16 bf16x4 __attribute__((ext_vector_type(4)));
typedef __bf16 bf16x8 __attribute__((ext_vector_type(8)));
typedef float  f32x16 __attribute__((ext_vector_type(16)));

#define MFMA32(a,b,c) __builtin_amdgcn_mfma_f32_32x32x16_bf16((a),(b),(c),0,0,0)

// ---------------- workspace layout (bytes) ----------------
#define OFF_META 0
#define OFF_PERM 8192
#define OFF_WM1  (128*1024)
#define OFF_WM2  (OFF_WM1 + NAG*HID*HID*2)
#define OFF_WM3  (OFF_WM2 + NAG*HID*HID*2)
#define OFF_WM4  (OFF_WM3 + NAG*HID*HID*2)
#define OFF_WIH  (OFF_WM4 + NAG*NACT*HID*2)
#define OFF_WHH  (OFF_WIH + 3*HID*HID*2)
#define OFF_XS   (OFF_WHH + 3*HID*HID*2)        // h (gru out, sorted bf16); then q3
#define OFF_B1   (OFF_XS + (size_t)NR*HID*2)    // x1 (fc1 out); then q2

// ---------------- helpers ----------------
__device__ inline void load_lds16(const void* g, void* l) {
  __builtin_amdgcn_global_load_lds((__attribute__((address_space(1))) void*)g,
                                   (__attribute__((address_space(3))) void*)l,
                                   16, 0, 0);
}

// LDS tile: [R rows][64 bf16], 128B/row; 16B slot s of row r holds col-block (s ^ (r&7))
__device__ inline bf16x8 lds_frag(const bf16_t* base, int r, int cb) {
  return *(const bf16x8*)((const char*)base + r*128 + ((cb*16) ^ ((r&7)<<4)));
}
__device__ inline void store8bf(void* dst, float4 a, float4 b) {
  union { bf16_t h[8]; uint4 u; } p;
  p.h[0]=(bf16_t)a.x; p.h[1]=(bf16_t)a.y; p.h[2]=(bf16_t)a.z; p.h[3]=(bf16_t)a.w;
  p.h[4]=(bf16_t)b.x; p.h[5]=(bf16_t)b.y; p.h[6]=(bf16_t)b.z; p.h[7]=(bf16_t)b.w;
  *(uint4*)dst = p.u;
}
__device__ inline float kmask(float w, float t) {
  // t <= -3 always: sigmoid(t) = x/(1+x), x=e^t<=0.05 -> x - x^2 + x^3 (err <= 6e-6)
  float x = __expf(t);
  float x2 = x*x;
  float s = x - x2 + x2*x;
  float m = fabsf(w) - s;
  return m > 0.f ? copysignf(m, w) : 0.f;
}
__device__ inline float sigm(float x) { return 1.f / (1.f + __expf(-x)); }
__device__ inline float tanh_f(float x) {
  float e = __expf(2.f * fabsf(x));
  return copysignf(1.f - 2.f/(e + 1.f), x);
}

// ---------------- weight prep ----------------
__global__ void k_prep(const float* __restrict__ f1w, const float* __restrict__ f1t,
                       const float* __restrict__ f2w, const float* __restrict__ f2t,
                       const float* __restrict__ f3w, const float* __restrict__ f3t,
                       const float* __restrict__ f4w, const float* __restrict__ f4t,
                       const float* __restrict__ gih, const float* __restrict__ ghh,
                       bf16_t* __restrict__ wm1, bf16_t* __restrict__ wm2,
                       bf16_t* __restrict__ wm3, bf16_t* __restrict__ wm4,
                       bf16_t* __restrict__ wihb, bf16_t* __restrict__ whhb,
                       int* __restrict__ meta)
{
  const int tid = threadIdx.x;
  if (blockIdx.x == 0 && tid < 32) meta[tid] = 0;
  long v = (long)blockIdx.x * 256 + tid;
  const long VR1 = 524288;
  if (v < 3*VR1) {
    int which = (int)(v / VR1);
    long e = (v - (long)which*VR1) * 4;
    const float* W = which==0 ? f1w : (which==1 ? f2w : f3w);
    const float* T = which==0 ? f1t : (which==1 ? f2t : f3t);
    bf16_t* O = which==0 ? wm1 : (which==1 ? wm2 : wm3);
    long oi = e & (long)(HID*HID - 1);
    float4 w = *(const float4*)(W + oi);
    float4 t = *(const float4*)(T + e);
    bf16x4 o;
    o[0]=(bf16_t)kmask(w.x,t.x); o[1]=(bf16_t)kmask(w.y,t.y);
    o[2]=(bf16_t)kmask(w.z,t.z); o[3]=(bf16_t)kmask(w.w,t.w);
    *(bf16x4*)(O + e) = o;
  } else if (v < 3*VR1 + 65536) {
    long e = (v - 3*VR1) * 4;
    long oi = e & (long)(NACT*HID - 1);
    float4 w = *(const float4*)(f4w + oi);
    float4 t = *(const float4*)(f4t + e);
    bf16x4 o;
    o[0]=(bf16_t)kmask(w.x,t.x); o[1]=(bf16_t)kmask(w.y,t.y);
    o[2]=(bf16_t)kmask(w.z,t.z); o[3]=(bf16_t)kmask(w.w,t.w);
    *(bf16x4*)(wm4 + e) = o;
  } else if (v < 3*VR1 + 65536 + 196608) {
    long e = (v - (3*VR1 + 65536)) * 4;
    float4 x = *(const float4*)(gih + e);
    bf16x4 o; o[0]=(bf16_t)x.x; o[1]=(bf16_t)x.y; o[2]=(bf16_t)x.z; o[3]=(bf16_t)x.w;
    *(bf16x4*)(wihb + e) = o;
  } else if (v < 3*VR1 + 65536 + 2*196608) {
    long e = (v - (3*VR1 + 65536 + 196608)) * 4;
    float4 x = *(const float4*)(ghh + e);
    bf16x4 o; o[0]=(bf16_t)x.x; o[1]=(bf16_t)x.y; o[2]=(bf16_t)x.z; o[3]=(bf16_t)x.w;
    *(bf16x4*)(whhb + e) = o;
  }
}

// ---------------- bucket rows by agent ----------------
__global__ void k_count(const int* __restrict__ ids, int* __restrict__ meta) {
  int n = blockIdx.x*256 + threadIdx.x;
  atomicAdd(&meta[ids[n]], 1);
}

__global__ void k_td(int* __restrict__ meta) {
  int off = 0, nt = 0, nt64 = 0;
  for (int a = 0; a < NAG; ++a) {
    int c = meta[a];
    meta[8+a] = off;
    for (int t = 0; t*128 < c; ++t) {
      meta[32  + nt] = off + t*128;
      meta[192 + nt] = (c - t*128 < 128) ? (c - t*128) : 128;
      meta[352 + nt] = a;
      ++nt;
    }
    for (int t = 0; t*64 < c; ++t) {
      meta[512  + nt64] = off + t*64;
      meta[800  + nt64] = (c - t*64 < 64) ? (c - t*64) : 64;
      meta[1088 + nt64] = a;
      ++nt64;
    }
    off += c;
  }
  meta[16] = nt;
  meta[17] = nt64;
}

__global__ void k_scatter(const int* __restrict__ ids, int* __restrict__ meta,
                          int* __restrict__ perm) {
  int n = blockIdx.x*256 + threadIdx.x;
  int a = ids[n];
  int pos = atomicAdd(&meta[8+a], 1);
  perm[pos] = n;
}

// ---------------- grouped kalei GEMM: BM=128, BN=128, 4 waves, single-buffer ----------------
template<bool GATHER>
__global__ __launch_bounds__(256, 4)
void k_fc(const float* __restrict__ a_f32, const bf16_t* __restrict__ a_bf,
          const bf16_t* __restrict__ wbase, const float* __restrict__ bias,
          bf16_t* __restrict__ out_bf,
          const int* __restrict__ meta, const int* __restrict__ perm)
{
  const int bx = blockIdx.x;
  if (bx >= meta[16]) return;
  const int m0 = meta[32+bx], rows = meta[192+bx], agent = meta[352+bx];
  const int o0 = blockIdx.y * 128;
  const bf16_t* W = wbase + (size_t)agent * HID * HID;

  __shared__ bf16_t lA[128*64];
  __shared__ bf16_t lB[128*64];

  const int tid = threadIdx.x, lane = tid & 63, wid = tid >> 6;
  const int wrow = wid & 1, wcol = wid >> 1;
  const int gsw = (lane&7) ^ ((lane>>3)&7);
  const int lr8 = lane >> 3;

  f32x16 zero;
  #pragma unroll
  for (int i = 0; i < 16; ++i) zero[i] = 0.f;
  f32x16 acc[2][2];
  acc[0][0]=acc[0][1]=acc[1][0]=acc[1][1]=zero;

  for (int kp = 0; kp < 8; ++kp) {
    const int k0 = kp * 64;
    __syncthreads();
    if constexpr (GATHER) {
      #pragma unroll
      for (int it = 0; it < 4; ++it) {
        int t = it*256 + tid;
        int r = t >> 3, cb = t & 7;
        int rl = r < rows ? r : rows-1;
        const float* sp = a_f32 + (size_t)perm[m0+rl]*HID + k0 + cb*8;
        float4 v0 = ((const float4*)sp)[0];
        float4 v1 = ((const float4*)sp)[1];
        store8bf((char*)lA + r*128 + ((cb*16) ^ ((r&7)<<4)), v0, v1);
      }
    } else {
      #pragma unroll
      for (int i = 0; i < 4; ++i) {
        int c = wid*4 + i;
        int r = c*8 + lr8;
        int rl = r < rows ? r : rows-1;
        load_lds16(a_bf + (size_t)(m0+rl)*HID + k0 + gsw*8, (char*)lA + c*1024);
      }
    }
    #pragma unroll
    for (int i = 0; i < 4; ++i) {
      int c = wid*4 + i;
      int r = c*8 + lr8;
      load_lds16(W + (size_t)(o0+r)*HID + k0 + gsw*8, (char*)lB + c*1024);
    }
    __syncthreads();
    #pragma unroll
    for (int kk = 0; kk < 4; ++kk) {
      const int cbb = kk*2 + (lane>>5);
      bf16x8 af0 = lds_frag(lA, wrow*64 +      (lane&31), cbb);
      bf16x8 af1 = lds_frag(lA, wrow*64 + 32 + (lane&31), cbb);
      bf16x8 bv0 = lds_frag(lB, wcol*64 +      (lane&31), cbb);
      bf16x8 bv1 = lds_frag(lB, wcol*64 + 32 + (lane&31), cbb);
      __builtin_amdgcn_s_setprio(1);
      acc[0][0] = MFMA32(af0, bv0, acc[0][0]);
      acc[1][0] = MFMA32(af1, bv0, acc[1][0]);
      acc[0][1] = MFMA32(af0, bv1, acc[0][1]);
      acc[1][1] = MFMA32(af1, bv1, acc[1][1]);
      __builtin_amdgcn_s_setprio(0);
    }
  }

  // epilogue: relu(acc+b); C layout (32x32): col=lane&31, row=4*(lane>>5)+(g&3)+8*(g>>2)
  #pragma unroll
  for (int fn = 0; fn < 2; ++fn) {
    int col = o0 + wcol*64 + fn*32 + (lane&31);
    float bv = bias[col];
    #pragma unroll
    for (int fm = 0; fm < 2; ++fm) {
      #pragma unroll
      for (int g = 0; g < 16; ++g) {
        int rl = wrow*64 + fm*32 + 4*(lane>>5) + (g&3) + 8*(g>>2);
        if (rl < rows) {
          float y = fmaxf(acc[fm][fn][g] + bv, 0.f);
          out_bf[(size_t)(m0+rl)*HID + col] = (bf16_t)y;
        }
      }
    }
  }
}

// ---------------- fused GRU: BM=128, BN=64, 4 waves, single-buffer ----------------
// grid (128, 8); 40KB LDS -> 4 blocks/CU. Two statically-bound phase loops
// (rule #20: accumulator must be compile-time selected, never via runtime ptr).
__global__ __launch_bounds__(256, 4)
void k_gru(const bf16_t* __restrict__ x1, const float* __restrict__ hidden,
           const bf16_t* __restrict__ wih, const bf16_t* __restrict__ whh,
           const float* __restrict__ bih, const float* __restrict__ bhh,
           bf16_t* __restrict__ hbuf, float* __restrict__ hout,
           const int* __restrict__ perm)
{
  const int m0 = blockIdx.x * 128;
  const int j0 = blockIdx.y * 64;
  const int tid = threadIdx.x, lane = tid & 63, wid = tid >> 6;
  const int wrow = wid & 1, wcol = wid >> 1;
  const int gsw = (lane&7) ^ ((lane>>3)&7);
  const int lr8 = lane >> 3;

  __shared__ bf16_t lA[128*64];
  __shared__ bf16_t lB[192*64];

  f32x16 zero;
  #pragma unroll
  for (int i = 0; i < 16; ++i) zero[i] = 0.f;
  f32x16 ar[2], az[2], an[2], ah[2];
  ar[0]=ar[1]=az[0]=az[1]=an[0]=an[1]=ah[0]=ah[1]=zero;

  auto stageB = [&](const bf16_t* Wg, int k0) {
    #pragma unroll
    for (int i = 0; i < 6; ++i) {
      int c = wid*6 + i;                // 24 chunks: rows 0..191 = gate*64 + within
      int r = c*8 + lr8;
      int wr = (r>>6)*HID + j0 + (r&63);
      load_lds16(Wg + (size_t)wr*HID + k0 + gsw*8, (char*)lB + c*1024);
    }
  };

  auto compute = [&](f32x16 (&a3)[2]) {
    #pragma unroll
    for (int kk = 0; kk < 4; ++kk) {
      const int cbb = kk*2 + (lane>>5);
      bf16x8 af0 = lds_frag(lA, wrow*64 +      (lane&31), cbb);
      bf16x8 af1 = lds_frag(lA, wrow*64 + 32 + (lane&31), cbb);
      const int rb = wcol*32 + (lane&31);
      bf16x8 b0 = lds_frag(lB,        rb, cbb);
      bf16x8 b1 = lds_frag(lB + 4096, rb, cbb);
      bf16x8 b2 = lds_frag(lB + 8192, rb, cbb);
      __builtin_amdgcn_s_setprio(1);
      ar[0] = MFMA32(af0, b0, ar[0]); ar[1] = MFMA32(af1, b0, ar[1]);
      az[0] = MFMA32(af0, b1, az[0]); az[1] = MFMA32(af1, b1, az[1]);
      a3[0] = MFMA32(af0, b2, a3[0]); a3[1] = MFMA32(af1, b2, a3[1]);
      __builtin_amdgcn_s_setprio(0);
    }
  };

  // ---- X phase: A = x1 (sorted bf16) via glds; accumulate ar, az, an ----
  for (int kp = 0; kp < 8; ++kp) {
    const int k0 = kp * 64;
    __syncthreads();
    #pragma unroll
    for (int i = 0; i < 4; ++i) {
      int c = wid*4 + i;
      int r = c*8 + lr8;
      load_lds16(x1 + (size_t)(m0+r)*HID + k0 + gsw*8, (char*)lA + c*1024);
    }
    stageB(wih, k0);
    __syncthreads();
    compute(an);
  }
  // ---- H phase: A = hidden fp32 gathered via perm; accumulate ar, az, ah ----
  for (int kp = 0; kp < 8; ++kp) {
    const int k0 = kp * 64;
    __syncthreads();
    #pragma unroll
    for (int it = 0; it < 4; ++it) {
      int t = it*256 + tid;
      int r = t >> 3, cb = t & 7;
      const float* sp = hidden + (size_t)perm[m0+r]*HID + k0 + cb*8;
      float4 v0 = ((const float4*)sp)[0];
      float4 v1 = ((const float4*)sp)[1];
      store8bf((char*)lA + r*128 + ((cb*16) ^ ((r&7)<<4)), v0, v1);
    }
    stageB(whh, k0);
    __syncthreads();
    compute(ah);
  }

  // ---- epilogue: gates + blend (h_prev exact fp32) ----
  const int col = j0 + wcol*32 + (lane&31);
  const float b_r  = bih[col]        + bhh[col];
  const float b_z  = bih[512 + col]  + bhh[512 + col];
  const float b_in = bih[1024 + col];
  const float b_hn = bhh[1024 + col];
  #pragma unroll
  for (int fm = 0; fm < 2; ++fm) {
    #pragma unroll
    for (int g = 0; g < 16; ++g) {
      int rl = wrow*64 + fm*32 + 4*(lane>>5) + (g&3) + 8*(g>>2);
      int m = m0 + rl;
      int src = perm[m];
      float hp = hidden[(size_t)src*HID + col];
      float rg = sigm(ar[fm][g] + b_r);
      float zg = sigm(az[fm][g] + b_z);
      float ng = tanh_f(an[fm][g] + b_in + rg*(ah[fm][g] + b_hn));
      float h  = (1.f - zg)*ng + zg*hp;
      hbuf[(size_t)m*HID + col] = (bf16_t)h;
      hout[(size_t)src*HID + col] = h;
    }
  }
}

// ---------------- fc4: BM=64, BN=64, 4 waves (2x2, tile 32x32), single-buffer ----------------
__global__ __launch_bounds__(256, 4)
void k_fc4(const bf16_t* __restrict__ a_bf, const bf16_t* __restrict__ wbase,
           const float* __restrict__ bias, float* __restrict__ out_f32,
           const int* __restrict__ meta, const int* __restrict__ perm)
{
  const int bx = blockIdx.x;
  if (bx >= meta[17]) return;
  const int m0 = meta[512+bx], rows = meta[800+bx], agent = meta[1088+bx];
  const bf16_t* W = wbase + (size_t)agent * NACT * HID;

  __shared__ bf16_t lA[64*64];
  __shared__ bf16_t lB[64*64];

  const int tid = threadIdx.x, lane = tid & 63, wid = tid >> 6;
  const int wrow = wid & 1, wcol = wid >> 1;
  const int gsw = (lane&7) ^ ((lane>>3)&7);
  const int lr8 = lane >> 3;

  f32x16 acc;
  #pragma unroll
  for (int i = 0; i < 16; ++i) acc[i] = 0.f;

  for (int kp = 0; kp < 8; ++kp) {
    const int k0 = kp * 64;
    __syncthreads();
    #pragma unroll
    for (int i = 0; i < 2; ++i) {
      int c = wid*2 + i;
      int r = c*8 + lr8;
      int rl = r < rows ? r : rows-1;
      load_lds16(a_bf + (size_t)(m0+rl)*HID + k0 + gsw*8, (char*)lA + c*1024);
    }
    #pragma unroll
    for (int i = 0; i < 2; ++i) {
      int c = wid*2 + i;
      int r = c*8 + lr8;
      load_lds16(W + (size_t)r*HID + k0 + gsw*8, (char*)lB + c*1024);
    }
    __syncthreads();
    #pragma unroll
    for (int kk = 0; kk < 4; ++kk) {
      const int cbb = kk*2 + (lane>>5);
      bf16x8 af = lds_frag(lA, wrow*32 + (lane&31), cbb);
      bf16x8 bv = lds_frag(lB, wcol*32 + (lane&31), cbb);
      __builtin_amdgcn_s_setprio(1);
      acc = MFMA32(af, bv, acc);
      __builtin_amdgcn_s_setprio(0);
    }
  }

  int col = wcol*32 + (lane&31);
  float bv = bias[col];
  #pragma unroll
  for (int g = 0; g < 16; ++g) {
    int rl = wrow*32 + 4*(lane>>5) + (g&3) + 8*(g>>2);
    if (rl < rows)
      out_f32[(size_t)perm[m0+rl]*NACT + col] = acc[g] + bv;
  }
}

// ---------------- launch ----------------
extern "C" void kernel_launch(void* const* d_in, const int* in_sizes, int n_in,
                              void* d_out, int out_size, void* d_ws, size_t ws_size,
                              hipStream_t stream) {
  const float* inputs  = (const float*)d_in[0];
  const float* hidden  = (const float*)d_in[1];
  const int*   ids     = (const int*)  d_in[2];
  const float* fc1_w   = (const float*)d_in[3];
  const float* fc1_b   = (const float*)d_in[4];
  const float* fc1_t   = (const float*)d_in[5];
  const float* gru_wih = (const float*)d_in[6];
  const float* gru_whh = (const float*)d_in[7];
  const float* gru_bih = (const float*)d_in[8];
  const float* gru_bhh = (const float*)d_in[9];
  const float* fc2_w   = (const float*)d_in[10];
  const float* fc2_b   = (const float*)d_in[11];
  const float* fc2_t   = (const float*)d_in[12];
  const float* fc3_w   = (const float*)d_in[13];
  const float* fc3_b   = (const float*)d_in[14];
  const float* fc3_t   = (const float*)d_in[15];
  const float* fc4_w   = (const float*)d_in[16];
  const float* fc4_b   = (const float*)d_in[17];
  const float* fc4_t   = (const float*)d_in[18];

  char* ws = (char*)d_ws;
  int*    meta = (int*)   (ws + OFF_META);
  int*    perm = (int*)   (ws + OFF_PERM);
  bf16_t* wm1  = (bf16_t*)(ws + OFF_WM1);
  bf16_t* wm2  = (bf16_t*)(ws + OFF_WM2);
  bf16_t* wm3  = (bf16_t*)(ws + OFF_WM3);
  bf16_t* wm4  = (bf16_t*)(ws + OFF_WM4);
  bf16_t* wihb = (bf16_t*)(ws + OFF_WIH);
  bf16_t* whhb = (bf16_t*)(ws + OFF_WHH);
  bf16_t* xs   = (bf16_t*)(ws + OFF_XS);   // h, then q3
  bf16_t* b1   = (bf16_t*)(ws + OFF_B1);   // x1, then q2

  float* q_out = (float*)d_out;                 // [NR][64]
  float* h_out = q_out + (size_t)NR * NACT;     // [NR][512]

  k_prep<<<7936, 256, 0, stream>>>(fc1_w, fc1_t, fc2_w, fc2_t, fc3_w, fc3_t,
                                   fc4_w, fc4_t, gru_wih, gru_whh,
                                   wm1, wm2, wm3, wm4, wihb, whhb, meta);
  k_count<<<64, 256, 0, stream>>>(ids, meta);
  k_td<<<1, 1, 0, stream>>>(meta);
  k_scatter<<<64, 256, 0, stream>>>(ids, meta, perm);

  // fc1: gather fp32 inputs -> b1 (x1 sorted bf16)
  k_fc<true><<<dim3(MAXT128, 4), 256, 0, stream>>>(
      inputs, nullptr, wm1, fc1_b, b1, meta, perm);
  // GRU: b1 + gathered hidden -> xs (h sorted bf16) + h_out (fp32 scattered)
  k_gru<<<dim3(NR/128, 8), 256, 0, stream>>>(b1, hidden, wihb, whhb,
                                             gru_bih, gru_bhh, xs, h_out, perm);
  // fc2: xs -> b1 (q2)
  k_fc<false><<<dim3(MAXT128, 4), 256, 0, stream>>>(
      nullptr, xs, wm2, fc2_b, b1, meta, perm);
  // fc3: b1 -> xs (q3)
  k_fc<false><<<dim3(MAXT128, 4), 256, 0, stream>>>(
      nullptr, b1, wm3, fc3_b, xs, meta, perm);
  // fc4: xs -> q_out (fp32 scattered, no relu)
  k_fc4<<<dim3(MAXT64, 1), 256, 0, stream>>>(xs, wm4, fc4_b, q_out, meta, perm);
}